// Round 1
// baseline (335.952 us; speedup 1.0000x reference)
//
#include <hip/hip_runtime.h>
#include <hip/hip_bf16.h>

typedef __bf16 bf16;
typedef bf16 bf16x8 __attribute__((ext_vector_type(8)));
typedef float f32x4 __attribute__((ext_vector_type(4)));

#define BM   64
#define FIN  128
#define FOUT 128
#define FANIN 640
#define LDA  136   // padded LDS row stride (bf16 elems): 128 + 8 keeps 16B align, 2-way max conflict

__global__ __launch_bounds__(256)
void mcc_kernel(const float* __restrict__ x,
                const int* __restrict__ nbr,
                const float* __restrict__ W,
                const float* __restrict__ bias,
                float* __restrict__ out,
                int N)
{
    __shared__ __align__(16) bf16 Asm[BM][LDA];
    __shared__ __align__(16) bf16 Bsm[FOUT][LDA];

    const int tid  = threadIdx.x;
    const int m0   = blockIdx.x * BM;
    const int wave = tid >> 6;
    const int lane = tid & 63;
    const int quad = lane >> 4;
    const int l16  = lane & 15;

    f32x4 acc[8] = {};

    // staging roles
    const int arow  = tid >> 2;   // 0..63  (A: one x row per 4 threads)
    const int asub  = tid & 3;    // 0..3
    const int brow  = tid >> 1;   // 0..127 (B: one W row per 2 threads)
    const int bhalf = tid & 1;    // 0..1

    for (int j = 0; j < 5; ++j) {
        // ---- stage B chunk: W[n][j*128 .. j*128+127] -> bf16 LDS ----
        {
            const float4* src = (const float4*)(W + (long)brow * FANIN + j * FIN + bhalf * 64);
            bf16* dst = &Bsm[brow][bhalf * 64];
            #pragma unroll
            for (int i = 0; i < 16; ++i) {
                float4 v = src[i];
                dst[i * 4 + 0] = (bf16)v.x;
                dst[i * 4 + 1] = (bf16)v.y;
                dst[i * 4 + 2] = (bf16)v.z;
                dst[i * 4 + 3] = (bf16)v.w;
            }
        }
        // ---- stage A chunk: gathered x rows -> bf16 LDS ----
        {
            int node = m0 + arow;
            int nc   = node < N ? node : N - 1;
            long long g = (j == 0) ? (long long)nc : (long long)nbr[(long long)nc * 4 + (j - 1)];
            const float4* src = (const float4*)(x + g * FIN);
            #pragma unroll
            for (int i = 0; i < 8; ++i) {
                int c4 = asub + i * 4;               // float4 index 0..31, 64B-coalesced per 4-thread group
                float4 v = src[c4];
                bf16* dst = &Asm[arow][c4 * 4];
                dst[0] = (bf16)v.x;
                dst[1] = (bf16)v.y;
                dst[2] = (bf16)v.z;
                dst[3] = (bf16)v.w;
            }
        }
        __syncthreads();

        // ---- MFMA over this 128-wide K chunk ----
        #pragma unroll
        for (int kk = 0; kk < 4; ++kk) {
            bf16x8 a = *(const bf16x8*)&Asm[wave * 16 + l16][kk * 32 + quad * 8];
            #pragma unroll
            for (int nt = 0; nt < 8; ++nt) {
                bf16x8 b = *(const bf16x8*)&Bsm[nt * 16 + l16][kk * 32 + quad * 8];
                acc[nt] = __builtin_amdgcn_mfma_f32_16x16x32_bf16(a, b, acc[nt], 0, 0, 0);
            }
        }
        __syncthreads();
    }

    // ---- epilogue: C layout col=lane&15, row=quad*4+reg ----
    const int m_local = wave * 16 + quad * 4;
    #pragma unroll
    for (int nt = 0; nt < 8; ++nt) {
        int n = nt * 16 + l16;
        float bv = bias[n];
        #pragma unroll
        for (int r = 0; r < 4; ++r) {
            int node = m0 + m_local + r;
            if (node < N)
                out[(long)node * FOUT + n] = acc[nt][r] + bv;
        }
    }
}

extern "C" void kernel_launch(void* const* d_in, const int* in_sizes, int n_in,
                              void* d_out, int out_size, void* d_ws, size_t ws_size,
                              hipStream_t stream) {
    const float* x    = (const float*)d_in[0];
    const int*   nbr  = (const int*)d_in[1];    // harness delivers integer inputs as int32
    const float* W    = (const float*)d_in[2];
    const float* bias = (const float*)d_in[3];
    float* out = (float*)d_out;

    int N = in_sizes[0] / FIN;                  // 200000
    int grid = (N + BM - 1) / BM;               // 3125
    mcc_kernel<<<grid, 256, 0, stream>>>(x, nbr, W, bias, out, N);
}

// Round 2
// 237.814 us; speedup vs baseline: 1.4127x; 1.4127x over previous
//
#include <hip/hip_runtime.h>
#include <hip/hip_bf16.h>
#include <stdint.h>

typedef __bf16 bf16;
typedef bf16 bf16x4 __attribute__((ext_vector_type(4)));
typedef bf16 bf16x8 __attribute__((ext_vector_type(8)));
typedef float f32x4 __attribute__((ext_vector_type(4)));

#define FIN   128
#define FOUT  128
#define FANIN 640
#define BM    128

// async 16B global->LDS (direct-to-shared DMA). LDS dest = uniform base + lane*16.
__device__ __forceinline__ void async16(const void* g, void* l) {
    __builtin_amdgcn_global_load_lds((const __attribute__((address_space(1))) void*)g,
                                     (__attribute__((address_space(3))) void*)l,
                                     16, 0, 0);
}

// ---------------- convert fp32 -> bf16 (x and W) ----------------
__global__ __launch_bounds__(256)
void convert_kernel(const float* __restrict__ x, const float* __restrict__ W,
                    bf16* __restrict__ xb, bf16* __restrict__ wb,
                    long nx4, long ntot4)
{
    long i = (long)blockIdx.x * 256 + threadIdx.x;   // float4 index
    if (i >= ntot4) return;
    float4 v;
    bf16* dst;
    if (i < nx4) { v = ((const float4*)x)[i];        dst = xb + i * 4; }
    else         { long k = i - nx4;
                   v = ((const float4*)W)[k];        dst = wb + k * 4; }
    bf16x4 h = { (bf16)v.x, (bf16)v.y, (bf16)v.z, (bf16)v.w };
    *(bf16x4*)dst = h;
}

// ---------------- main gather-GEMM, m97-style ----------------
// C[128 x 128] per block; K = 5 chunks of 128 (chunk j = gather slot j).
// A/B staged via global_load_lds(16B); XOR swizzle (chunk ^ row&15) baked into
// the GLOBAL address so LDS rows stay 256B-contiguous yet ds_read_b128 sees
// only 2-way bank aliasing (free).
__global__ __launch_bounds__(256)
void mcc_mfma(const bf16* __restrict__ xb, const int* __restrict__ nbr,
              const bf16* __restrict__ wb, const float* __restrict__ bias,
              float* __restrict__ out, int N)
{
    __shared__ __align__(16) bf16 Asm[BM][128];    // 32 KB
    __shared__ __align__(16) bf16 Bsm[FOUT][128];  // 32 KB
    __shared__ int nbrS[BM * 4];                   // 2 KB

    const int tid  = threadIdx.x;
    const int wave = tid >> 6;
    const int lane = tid & 63;
    const int quad = lane >> 4;
    const int l16  = lane & 15;
    const int wr   = wave >> 1;      // wave row 0..1 (64 rows each)
    const int wc   = wave & 1;       // wave col 0..1 (64 cols each)
    const int m0   = blockIdx.x * BM;

    // preload neighbor indices for this block's rows (clamped for the tail block)
    for (int t = tid; t < BM * 4; t += 256) {
        int node = m0 + (t >> 2);
        node = node < N ? node : N - 1;
        nbrS[t] = nbr[(long)node * 4 + (t & 3)];
    }
    __syncthreads();

    f32x4 acc[4][4] = {};

    const int rsub = lane >> 4;      // row-within-instruction 0..3
    const int c16  = lane & 15;      // 16B-chunk index 0..15

    for (int j = 0; j < 5; ++j) {
        // ---- stage A: 32 rows per wave, 4 rows (1 KB LDS) per instruction ----
        #pragma unroll
        for (int i = 0; i < 8; ++i) {
            int tr   = wave * 32 + i * 4 + rsub;           // tile row 0..127
            int node = m0 + tr;
            node = node < N ? node : N - 1;
            int g = (j == 0) ? node : nbrS[tr * 4 + (j - 1)];
            const char* gp = (const char*)xb + ((long)g << 8)           // row * 256B
                             + ((c16 ^ (tr & 15)) << 4);                 // swizzled chunk
            async16(gp, &Asm[wave * 32 + i * 4][0]);
        }
        // ---- stage B: W rows, chunk j ----
        #pragma unroll
        for (int i = 0; i < 8; ++i) {
            int br = wave * 32 + i * 4 + rsub;             // W row 0..127
            const char* gp = (const char*)wb + (long)br * (FANIN * 2)   // row * 1280B
                             + j * 256                                   // chunk offset
                             + ((c16 ^ (br & 15)) << 4);
            async16(gp, &Bsm[wave * 32 + i * 4][0]);
        }
        __syncthreads();

        // ---- MFMA over this 128-wide K chunk ----
        #pragma unroll
        for (int kk = 0; kk < 4; ++kk) {
            bf16x8 a[4], b[4];
            #pragma unroll
            for (int mi = 0; mi < 4; ++mi) {
                int ar = wr * 64 + mi * 16 + l16;          // ar & 15 == l16
                a[mi] = *(const bf16x8*)&Asm[ar][((kk * 4 + quad) ^ l16) << 3];
            }
            #pragma unroll
            for (int ni = 0; ni < 4; ++ni) {
                int br = wc * 64 + ni * 16 + l16;          // br & 15 == l16
                b[ni] = *(const bf16x8*)&Bsm[br][((kk * 4 + quad) ^ l16) << 3];
            }
            #pragma unroll
            for (int mi = 0; mi < 4; ++mi)
                #pragma unroll
                for (int ni = 0; ni < 4; ++ni)
                    acc[mi][ni] = __builtin_amdgcn_mfma_f32_16x16x32_bf16(
                                      a[mi], b[ni], acc[mi][ni], 0, 0, 0);
        }
        __syncthreads();
    }

    // ---- epilogue: C layout col=lane&15, row=quad*4+reg ----
    float bv[4];
    #pragma unroll
    for (int ni = 0; ni < 4; ++ni) bv[ni] = bias[wc * 64 + ni * 16 + l16];

    #pragma unroll
    for (int mi = 0; mi < 4; ++mi) {
        #pragma unroll
        for (int r = 0; r < 4; ++r) {
            int row = m0 + wr * 64 + mi * 16 + quad * 4 + r;
            if (row < N) {
                #pragma unroll
                for (int ni = 0; ni < 4; ++ni) {
                    int n = wc * 64 + ni * 16 + l16;
                    out[(long)row * FOUT + n] = acc[mi][ni][r] + bv[ni];
                }
            }
        }
    }
}

// ---------------- round-1 fallback (used only if ws_size too small) ----------------
#define FBM 64
#define LDA 136
__global__ __launch_bounds__(256)
void mcc_fallback(const float* __restrict__ x, const int* __restrict__ nbr,
                  const float* __restrict__ W, const float* __restrict__ bias,
                  float* __restrict__ out, int N)
{
    __shared__ __align__(16) bf16 As[FBM][LDA];
    __shared__ __align__(16) bf16 Bs[FOUT][LDA];
    const int tid = threadIdx.x;
    const int m0 = blockIdx.x * FBM;
    const int wave = tid >> 6, lane = tid & 63, quad = lane >> 4, l16 = lane & 15;
    f32x4 acc[8] = {};
    const int arow = tid >> 2, asub = tid & 3, brow = tid >> 1, bhalf = tid & 1;
    for (int j = 0; j < 5; ++j) {
        {
            const float4* src = (const float4*)(W + (long)brow * FANIN + j * FIN + bhalf * 64);
            bf16* dst = &Bs[brow][bhalf * 64];
            #pragma unroll
            for (int i = 0; i < 16; ++i) {
                float4 v = src[i];
                dst[i*4+0]=(bf16)v.x; dst[i*4+1]=(bf16)v.y; dst[i*4+2]=(bf16)v.z; dst[i*4+3]=(bf16)v.w;
            }
        }
        {
            int node = m0 + arow; int nc = node < N ? node : N - 1;
            long long g = (j == 0) ? (long long)nc : (long long)nbr[(long long)nc * 4 + (j - 1)];
            const float4* src = (const float4*)(x + g * FIN);
            #pragma unroll
            for (int i = 0; i < 8; ++i) {
                int c4 = asub + i * 4;
                float4 v = src[c4];
                bf16* dst = &As[arow][c4 * 4];
                dst[0]=(bf16)v.x; dst[1]=(bf16)v.y; dst[2]=(bf16)v.z; dst[3]=(bf16)v.w;
            }
        }
        __syncthreads();
        #pragma unroll
        for (int kk = 0; kk < 4; ++kk) {
            bf16x8 a = *(const bf16x8*)&As[wave * 16 + l16][kk * 32 + quad * 8];
            #pragma unroll
            for (int nt = 0; nt < 8; ++nt) {
                bf16x8 b = *(const bf16x8*)&Bs[nt * 16 + l16][kk * 32 + quad * 8];
                acc[nt] = __builtin_amdgcn_mfma_f32_16x16x32_bf16(a, b, acc[nt], 0, 0, 0);
            }
        }
        __syncthreads();
    }
    const int m_local = wave * 16 + quad * 4;
    #pragma unroll
    for (int nt = 0; nt < 8; ++nt) {
        int n = nt * 16 + l16;
        float bvv = bias[n];
        #pragma unroll
        for (int r = 0; r < 4; ++r) {
            int node = m0 + m_local + r;
            if (node < N) out[(long)node * FOUT + n] = acc[nt][r] + bvv;
        }
    }
}

extern "C" void kernel_launch(void* const* d_in, const int* in_sizes, int n_in,
                              void* d_out, int out_size, void* d_ws, size_t ws_size,
                              hipStream_t stream) {
    const float* x    = (const float*)d_in[0];
    const int*   nbr  = (const int*)d_in[1];
    const float* W    = (const float*)d_in[2];
    const float* bias = (const float*)d_in[3];
    float* out = (float*)d_out;

    int N = in_sizes[0] / FIN;                              // 200000
    size_t xb_bytes = (size_t)N * FIN * sizeof(bf16);       // 51.2 MB
    size_t wb_bytes = (size_t)FOUT * FANIN * sizeof(bf16);  // 160 KB

    if (ws_size >= xb_bytes + wb_bytes) {
        bf16* xb = (bf16*)d_ws;
        bf16* wb = (bf16*)((char*)d_ws + xb_bytes);
        long nx4   = (long)N * FIN / 4;
        long ntot4 = nx4 + (long)FOUT * FANIN / 4;
        int cgrid = (int)((ntot4 + 255) / 256);
        convert_kernel<<<cgrid, 256, 0, stream>>>(x, W, xb, wb, nx4, ntot4);
        int grid = (N + BM - 1) / BM;                       // 1563
        mcc_mfma<<<grid, 256, 0, stream>>>(xb, nbr, wb, bias, out, N);
    } else {
        int grid = (N + FBM - 1) / FBM;
        mcc_fallback<<<grid, 256, 0, stream>>>(x, nbr, W, bias, out, N);
    }
}

// Round 4
// 230.081 us; speedup vs baseline: 1.4601x; 1.0336x over previous
//
#include <hip/hip_runtime.h>
#include <hip/hip_bf16.h>
#include <stdint.h>

typedef __bf16 bf16;
typedef bf16 bf16x4 __attribute__((ext_vector_type(4)));
typedef bf16 bf16x8 __attribute__((ext_vector_type(8)));
typedef float f32x4 __attribute__((ext_vector_type(4)));
typedef float fv4 __attribute__((ext_vector_type(4)));   // native clang vector for nontemporal builtins

#define FIN   128
#define FOUT  128
#define FANIN 640
#define BM    128
#define BK    64      // K sub-chunk (bf16 elems) -> A/B LDS tiles 16KB each, 32KB total

__device__ __forceinline__ void async16(const void* g, void* l) {
    __builtin_amdgcn_global_load_lds((const __attribute__((address_space(1))) void*)g,
                                     (__attribute__((address_space(3))) void*)l,
                                     16, 0, 0);
}

// ---------------- convert fp32 -> bf16 (x and W), non-temporal reads ----------------
__global__ __launch_bounds__(256)
void convert_kernel(const float* __restrict__ x, const float* __restrict__ W,
                    bf16* __restrict__ xb, bf16* __restrict__ wb,
                    long nx4, long ntot4)
{
    long i = (long)blockIdx.x * 256 + threadIdx.x;   // float4 index
    if (i >= ntot4) return;
    fv4 v;
    bf16* dst;
    if (i < nx4) { v = __builtin_nontemporal_load((const fv4*)x + i); dst = xb + i * 4; }
    else         { long k = i - nx4;
                   v = __builtin_nontemporal_load((const fv4*)W + k); dst = wb + k * 4; }
    bf16x4 h = { (bf16)v.x, (bf16)v.y, (bf16)v.z, (bf16)v.w };
    *(bf16x4*)dst = h;
}

// ---------------- gather-GEMM, m97 shape: 128x128 tile, BK=64, 32KB LDS ----------------
// K = 10 sub-chunks of 64 (gather slot j = c>>1, half h = c&1).
// Neighbor ids preloaded to VGPRs (no LDS nbr table -> LDS exactly 32KB -> 4-5 blocks/CU).
// XOR swizzle (16B-chunk ^ row&7) baked into the GLOBAL address of global_load_lds so
// LDS rows stay contiguous yet ds_read_b128 sees only 2-way bank aliasing (free).
__global__ __launch_bounds__(256)
void mcc_mfma(const bf16* __restrict__ xb, const int* __restrict__ nbr,
              const bf16* __restrict__ wb, const float* __restrict__ bias,
              float* __restrict__ out, int N)
{
    __shared__ __align__(16) bf16 Asm[BM][BK];     // 16 KB
    __shared__ __align__(16) bf16 Bsm[FOUT][BK];   // 16 KB

    const int tid  = threadIdx.x;
    const int wave = tid >> 6;
    const int lane = tid & 63;
    const int quad = lane >> 4;
    const int l16  = lane & 15;
    const int wr   = wave >> 1;      // wave row 0..1 (64 out-rows each)
    const int wc   = wave & 1;       // wave col 0..1 (64 out-cols each)
    const int m0   = blockIdx.x * BM;

    const int r8 = lane >> 3;        // row-within-staging-instr 0..7
    const int c8 = lane & 7;         // 16B chunk 0..7
    const int sw = (c8 ^ r8) << 4;   // swizzled chunk byte offset

    // preload gather row ids into VGPRs: gsel[i][j], i = staging instr, j = slot
    int gsel[4][5];
    #pragma unroll
    for (int i = 0; i < 4; ++i) {
        int tr   = wave * 32 + i * 8 + r8;
        int node = m0 + tr;
        node = node < N ? node : N - 1;
        gsel[i][0] = node;
        #pragma unroll
        for (int jj = 1; jj < 5; ++jj)
            gsel[i][jj] = nbr[(long)node * 4 + (jj - 1)];   // 8 lanes share addr (broadcast)
    }

    f32x4 acc[4][4] = {};

    for (int c = 0; c < 10; ++c) {
        const int j = c >> 1;        // gather slot
        const int h = c & 1;         // 128B half of the 256B row

        // ---- stage A: 8 rows (1KB) per async16, 4 per wave ----
        #pragma unroll
        for (int i = 0; i < 4; ++i) {
            const char* gp = (const char*)xb + ((long)gsel[i][j] << 8) + h * 128 + sw;
            async16(gp, &Asm[wave * 32 + i * 8][0]);
        }
        // ---- stage B: W rows, slot j, half h ----
        #pragma unroll
        for (int i = 0; i < 4; ++i) {
            int br = wave * 32 + i * 8 + r8;
            const char* gp = (const char*)wb + (long)br * (FANIN * 2) + j * 256 + h * 128 + sw;
            async16(gp, &Bsm[wave * 32 + i * 8][0]);
        }
        __syncthreads();

        // ---- MFMA over this 64-wide K chunk: 2 steps of K=32 ----
        #pragma unroll
        for (int s = 0; s < 2; ++s) {
            bf16x8 a[4], b[4];
            #pragma unroll
            for (int mi = 0; mi < 4; ++mi) {
                int ar = wr * 64 + mi * 16 + l16;
                a[mi] = *(const bf16x8*)&Asm[ar][(((s * 4 + quad) ^ (l16 & 7)) << 3)];
            }
            #pragma unroll
            for (int ni = 0; ni < 4; ++ni) {
                int br = wc * 64 + ni * 16 + l16;
                b[ni] = *(const bf16x8*)&Bsm[br][(((s * 4 + quad) ^ (l16 & 7)) << 3)];
            }
            #pragma unroll
            for (int mi = 0; mi < 4; ++mi)
                #pragma unroll
                for (int ni = 0; ni < 4; ++ni)
                    acc[mi][ni] = __builtin_amdgcn_mfma_f32_16x16x32_bf16(
                                      a[mi], b[ni], acc[mi][ni], 0, 0, 0);
        }
        __syncthreads();
    }

    // ---- epilogue: C layout col=lane&15, row=quad*4+reg; non-temporal stores ----
    float bv[4];
    #pragma unroll
    for (int ni = 0; ni < 4; ++ni) bv[ni] = bias[wc * 64 + ni * 16 + l16];

    #pragma unroll
    for (int mi = 0; mi < 4; ++mi) {
        #pragma unroll
        for (int r = 0; r < 4; ++r) {
            int row = m0 + wr * 64 + mi * 16 + quad * 4 + r;
            if (row < N) {
                #pragma unroll
                for (int ni = 0; ni < 4; ++ni) {
                    int n = wc * 64 + ni * 16 + l16;
                    __builtin_nontemporal_store(acc[mi][ni][r] + bv[ni],
                                                &out[(long)row * FOUT + n]);
                }
            }
        }
    }
}

// ---------------- round-1 fallback (used only if ws_size too small) ----------------
#define FBM 64
#define LDA 136
__global__ __launch_bounds__(256)
void mcc_fallback(const float* __restrict__ x, const int* __restrict__ nbr,
                  const float* __restrict__ W, const float* __restrict__ bias,
                  float* __restrict__ out, int N)
{
    __shared__ __align__(16) bf16 As[FBM][LDA];
    __shared__ __align__(16) bf16 Bs[FOUT][LDA];
    const int tid = threadIdx.x;
    const int m0 = blockIdx.x * FBM;
    const int wave = tid >> 6, lane = tid & 63, quad = lane >> 4, l16 = lane & 15;
    f32x4 acc[8] = {};
    const int arow = tid >> 2, asub = tid & 3, brow = tid >> 1, bhalf = tid & 1;
    for (int j = 0; j < 5; ++j) {
        {
            const float4* src = (const float4*)(W + (long)brow * FANIN + j * FIN + bhalf * 64);
            bf16* dst = &Bs[brow][bhalf * 64];
            #pragma unroll
            for (int i = 0; i < 16; ++i) {
                float4 v = src[i];
                dst[i*4+0]=(bf16)v.x; dst[i*4+1]=(bf16)v.y; dst[i*4+2]=(bf16)v.z; dst[i*4+3]=(bf16)v.w;
            }
        }
        {
            int node = m0 + arow; int nc = node < N ? node : N - 1;
            long long g = (j == 0) ? (long long)nc : (long long)nbr[(long long)nc * 4 + (j - 1)];
            const float4* src = (const float4*)(x + g * FIN);
            #pragma unroll
            for (int i = 0; i < 8; ++i) {
                int c4 = asub + i * 4;
                float4 v = src[c4];
                bf16* dst = &As[arow][c4 * 4];
                dst[0]=(bf16)v.x; dst[1]=(bf16)v.y; dst[2]=(bf16)v.z; dst[3]=(bf16)v.w;
            }
        }
        __syncthreads();
        #pragma unroll
        for (int kk = 0; kk < 4; ++kk) {
            bf16x8 a = *(const bf16x8*)&As[wave * 16 + l16][kk * 32 + quad * 8];
            #pragma unroll
            for (int nt = 0; nt < 8; ++nt) {
                bf16x8 b = *(const bf16x8*)&Bs[nt * 16 + l16][kk * 32 + quad * 8];
                acc[nt] = __builtin_amdgcn_mfma_f32_16x16x32_bf16(a, b, acc[nt], 0, 0, 0);
            }
        }
        __syncthreads();
    }
    const int m_local = wave * 16 + quad * 4;
    #pragma unroll
    for (int nt = 0; nt < 8; ++nt) {
        int n = nt * 16 + l16;
        float bvv = bias[n];
        #pragma unroll
        for (int r = 0; r < 4; ++r) {
            int node = m0 + m_local + r;
            if (node < N) out[(long)node * FOUT + n] = acc[nt][r] + bvv;
        }
    }
}

extern "C" void kernel_launch(void* const* d_in, const int* in_sizes, int n_in,
                              void* d_out, int out_size, void* d_ws, size_t ws_size,
                              hipStream_t stream) {
    const float* x    = (const float*)d_in[0];
    const int*   nbr  = (const int*)d_in[1];
    const float* W    = (const float*)d_in[2];
    const float* bias = (const float*)d_in[3];
    float* out = (float*)d_out;

    int N = in_sizes[0] / FIN;                              // 200000
    size_t xb_bytes = (size_t)N * FIN * sizeof(bf16);       // 51.2 MB
    size_t wb_bytes = (size_t)FOUT * FANIN * sizeof(bf16);  // 160 KB

    if (ws_size >= xb_bytes + wb_bytes) {
        bf16* xb = (bf16*)d_ws;
        bf16* wb = (bf16*)((char*)d_ws + xb_bytes);
        long nx4   = (long)N * FIN / 4;
        long ntot4 = nx4 + (long)FOUT * FANIN / 4;
        int cgrid = (int)((ntot4 + 255) / 256);
        convert_kernel<<<cgrid, 256, 0, stream>>>(x, W, xb, wb, nx4, ntot4);
        int grid = (N + BM - 1) / BM;                       // 1563
        mcc_mfma<<<grid, 256, 0, stream>>>(xb, nbr, wb, bias, out, N);
    } else {
        int grid = (N + FBM - 1) / FBM;
        mcc_fallback<<<grid, 256, 0, stream>>>(x, nbr, W, bias, out, N);
    }
}